// Round 3
// baseline (73.169 us; speedup 1.0000x reference)
//
#include <hip/hip_runtime.h>
#include <math.h>

typedef float v2f __attribute__((ext_vector_type(2)));

#define N_POINTS 32768
#define NUM_EMBED 8192
#define NPAIRS 4096
#define CHUNKS 16
#define PAIRS_PER_CHUNK (NPAIRS / CHUNKS)   // 256 pairs = 512 candidates per chunk
#define CSTRIDE 4096                         // 64*64, channel stride in z [B,C,H,W]

// ---------------- kernel A: build pair-interleaved codebook + ee (exact XLA arithmetic)
__global__ void vq_prep_kernel(const float4* __restrict__ E,
                               v2f* __restrict__ Epk, v2f* __restrict__ eev) {
    int p = blockIdx.x * 256 + threadIdx.x;
    if (p < NPAIRS) {
        float4 a = E[2 * p];
        float4 b = E[2 * p + 1];
        Epk[4 * p + 0] = (v2f){a.x, b.x};
        Epk[4 * p + 1] = (v2f){a.y, b.y};
        Epk[4 * p + 2] = (v2f){a.z, b.z};
        Epk[4 * p + 3] = (v2f){a.w, b.w};
        float ea = __fmul_rn(a.x, a.x);
        ea = __fadd_rn(ea, __fmul_rn(a.y, a.y));
        ea = __fadd_rn(ea, __fmul_rn(a.z, a.z));
        ea = __fadd_rn(ea, __fmul_rn(a.w, a.w));
        float eb = __fmul_rn(b.x, b.x);
        eb = __fadd_rn(eb, __fmul_rn(b.y, b.y));
        eb = __fadd_rn(eb, __fmul_rn(b.z, b.z));
        eb = __fadd_rn(eb, __fmul_rn(b.w, b.w));
        eev[p] = (v2f){ea, eb};
    }
}

// ---------------- kernel B: per (point, chunk) partial argmin, 2 candidates/iter, LDS-staged codebook
__global__ __launch_bounds__(256) void vq_partial_kernel(
        const float* __restrict__ z, const v2f* __restrict__ Epk,
        const v2f* __restrict__ eev,
        float* __restrict__ wd, int* __restrict__ wi) {
    __shared__ alignas(16) v2f sE[PAIRS_PER_CHUNK * 4];   // 8 KB: pair-interleaved e components
    __shared__ alignas(16) v2f see[PAIRS_PER_CHUNK];      // 2 KB: pair ee values

    int n = blockIdx.x * 256 + threadIdx.x;     // point id, lanes consecutive -> coalesced z
    int c = blockIdx.y;                          // candidate chunk

    // ---- stage chunk slice to LDS (coalesced float4 vector loads)
    {
        const float4* gE = (const float4*)(Epk + (size_t)c * PAIRS_PER_CHUNK * 4); // 512 float4
        float4* sE4 = (float4*)sE;
        sE4[threadIdx.x] = gE[threadIdx.x];
        sE4[256 + threadIdx.x] = gE[256 + threadIdx.x];
        if (threadIdx.x < 128) {
            const float4* ge2 = (const float4*)(eev + (size_t)c * PAIRS_PER_CHUNK); // 128 float4
            ((float4*)see)[threadIdx.x] = ge2[threadIdx.x];
        }
    }

    int b = n >> 12;
    int hw = n & 4095;
    const float* zp = z + b * 16384 + hw;
    float z0 = zp[0];
    float z1 = zp[CSTRIDE];
    float z2 = zp[2 * CSTRIDE];
    float z3 = zp[3 * CSTRIDE];
    // zz: mul + sequential adds (no contraction) — matches reference
    float zz = __fmul_rn(z0, z0);
    zz = __fadd_rn(zz, __fmul_rn(z1, z1));
    zz = __fadd_rn(zz, __fmul_rn(z2, z2));
    zz = __fadd_rn(zz, __fmul_rn(z3, z3));

    // hoisted broadcast pairs
    v2f z0v = {z0, z0}, z1v = {z1, z1}, z2v = {z2, z2}, z3v = {z3, z3};
    v2f zzv = {zz, zz};
    v2f m2v = {-2.0f, -2.0f};

    __syncthreads();

    float bdl = __builtin_inff(), bdh = __builtin_inff();
    int bpl = 0, bph = 0;
    const float4* sE4 = (const float4*)sE;
    #pragma unroll 32
    for (int t = 0; t < PAIRS_PER_CHUNK; ++t) {
        // uniform LDS reads -> hardware broadcast, no bank conflicts
        float4 E01 = sE4[2 * t];       // {e0.lo,e0.hi, e1.lo,e1.hi}
        float4 E23 = sE4[2 * t + 1];   // {e2.lo,e2.hi, e3.lo,e3.hi}
        v2f ee2 = see[t];
        v2f e0 = {E01.x, E01.y};
        v2f e1 = {E01.z, E01.w};
        v2f e2 = {E23.x, E23.y};
        v2f e3 = {E23.z, E23.w};
        // per-half arithmetic identical to the scalar reference chain:
        v2f szz = zzv + ee2;                                 // zz + ee_j   (rn)
        v2f dot = z0v * e0;                                  // z0*e0       (rn)
        dot = __builtin_elementwise_fma(z1v, e1, dot);       // fma chain ascending k
        dot = __builtin_elementwise_fma(z2v, e2, dot);
        dot = __builtin_elementwise_fma(z3v, e3, dot);
        v2f d2 = __builtin_elementwise_fma(m2v, dot, szz);   // (zz+ee) - 2*dot
        if (d2.x < bdl) { bdl = d2.x; bpl = t; }             // strict < : first index wins
        if (d2.y < bdh) { bdh = d2.y; bph = t; }
    }
    // resolve halves with global first-index tie-break
    const int p0 = c * PAIRS_PER_CHUNK;
    int il = 2 * (p0 + bpl), ih = 2 * (p0 + bph) + 1;
    float bestd; int besti;
    if (bdh < bdl) { bestd = bdh; besti = ih; }
    else           { bestd = bdl; besti = (bdl == bdh && ih < il) ? ih : il; }
    wd[c * N_POINTS + n] = bestd;
    wi[c * N_POINTS + n] = besti;
}

// ---------------- kernel C: combine chunks, write z_q_ste (NCHW), idx-as-float, loss partials
__global__ __launch_bounds__(256) void vq_finalize_kernel(
        const float* __restrict__ z, const float4* __restrict__ E,
        const float* __restrict__ wd, const int* __restrict__ wi,
        float* __restrict__ out, double* __restrict__ partial) {
    __shared__ double sdata[256];
    int n = blockIdx.x * 256 + threadIdx.x;
    float bestd = __builtin_inff();
    int besti = 0;
    #pragma unroll
    for (int c = 0; c < CHUNKS; ++c) {           // ascending chunk + strict < -> global first-min
        float d = wd[c * N_POINTS + n];
        int i = wi[c * N_POINTS + n];
        if (d < bestd) { bestd = d; besti = i; }
    }
    int b = n >> 12;
    int hw = n & 4095;
    const float* zp = z + b * 16384 + hw;
    float* op = out + b * 16384 + hw;
    float4 e = E[besti];
    float ec[4] = {e.x, e.y, e.z, e.w};
    double ds = 0.0;
    #pragma unroll
    for (int cc = 0; cc < 4; ++cc) {
        float zc = zp[cc * CSTRIDE];
        float t = __fsub_rn(ec[cc], zc);         // z_q - z (the sg'd diff, also loss diff)
        float q = __fadd_rn(zc, t);              // straight-through: z + (z_q - z)
        op[cc * CSTRIDE] = q;
        float t2 = __fmul_rn(t, t);
        ds += (double)t2;
    }
    out[131073 + n] = (float)besti;              // indices as float32 (exact)

    sdata[threadIdx.x] = ds;
    __syncthreads();
    #pragma unroll
    for (int s = 128; s > 0; s >>= 1) {
        if (threadIdx.x < s) sdata[threadIdx.x] += sdata[threadIdx.x + s];
        __syncthreads();
    }
    if (threadIdx.x == 0) partial[blockIdx.x] = sdata[0];
}

// ---------------- kernel D: deterministic loss reduce
__global__ void vq_loss_kernel(const double* __restrict__ partial, float* __restrict__ out) {
    __shared__ double sdata[128];
    int t = threadIdx.x;
    sdata[t] = partial[t];
    __syncthreads();
    #pragma unroll
    for (int s = 64; s > 0; s >>= 1) {
        if (t < s) sdata[t] += sdata[t + s];
        __syncthreads();
    }
    if (t == 0) {
        float m = (float)(sdata[0] / 131072.0);
        // loss = mean + BETA*mean (both means are numerically identical)
        out[131072] = __fadd_rn(m, __fmul_rn(0.25f, m));
    }
}

extern "C" void kernel_launch(void* const* d_in, const int* in_sizes, int n_in,
                              void* d_out, int out_size, void* d_ws, size_t ws_size,
                              hipStream_t stream) {
    const float* z = (const float*)d_in[0];
    const float4* E = (const float4*)d_in[1];
    float* out = (float*)d_out;

    char* ws = (char*)d_ws;
    v2f* Epk = (v2f*)ws;                                     // 4096*4 v2f = 128 KB
    v2f* eev = (v2f*)(ws + 131072);                          // 4096 v2f = 32 KB
    float* wd = (float*)(ws + 131072 + 32768);               // 16*32768 f32 = 2 MB
    int*   wi = (int*)(ws + 131072 + 32768 + (size_t)CHUNKS * N_POINTS * 4); // 2 MB
    double* partial = (double*)(ws + 131072 + 32768 + (size_t)CHUNKS * N_POINTS * 8); // 1 KB

    vq_prep_kernel<<<NPAIRS / 256, 256, 0, stream>>>(E, Epk, eev);
    vq_partial_kernel<<<dim3(N_POINTS / 256, CHUNKS), 256, 0, stream>>>(z, Epk, eev, wd, wi);
    vq_finalize_kernel<<<N_POINTS / 256, 256, 0, stream>>>(z, E, wd, wi, out, partial);
    vq_loss_kernel<<<1, 128, 0, stream>>>(partial, out);
}

// Round 4
// 69.035 us; speedup vs baseline: 1.0599x; 1.0599x over previous
//
#include <hip/hip_runtime.h>
#include <math.h>

typedef float v2f __attribute__((ext_vector_type(2)));

#define N_POINTS 32768
#define NUM_EMBED 8192
#define NPAIRS 4096
#define CHUNKS 16
#define PAIRS_PER_CHUNK (NPAIRS / CHUNKS)   // 256 pairs = 512 candidates per chunk
#define PPT 4                                // points per thread
#define CSTRIDE 4096                         // 64*64, channel stride in z [B,C,H,W]

// ---------------- kernel A: build pair-interleaved codebook + ee (exact XLA arithmetic)
__global__ void vq_prep_kernel(const float4* __restrict__ E,
                               v2f* __restrict__ Epk, v2f* __restrict__ eev) {
    int p = blockIdx.x * 256 + threadIdx.x;
    if (p < NPAIRS) {
        float4 a = E[2 * p];
        float4 b = E[2 * p + 1];
        Epk[4 * p + 0] = (v2f){a.x, b.x};
        Epk[4 * p + 1] = (v2f){a.y, b.y};
        Epk[4 * p + 2] = (v2f){a.z, b.z};
        Epk[4 * p + 3] = (v2f){a.w, b.w};
        float ea = __fmul_rn(a.x, a.x);
        ea = __fadd_rn(ea, __fmul_rn(a.y, a.y));
        ea = __fadd_rn(ea, __fmul_rn(a.z, a.z));
        ea = __fadd_rn(ea, __fmul_rn(a.w, a.w));
        float eb = __fmul_rn(b.x, b.x);
        eb = __fadd_rn(eb, __fmul_rn(b.y, b.y));
        eb = __fadd_rn(eb, __fmul_rn(b.z, b.z));
        eb = __fadd_rn(eb, __fmul_rn(b.w, b.w));
        eev[p] = (v2f){ea, eb};
    }
}

// packed f32 ops forced via inline asm (per-half IEEE rn, bit-identical to scalar chain)
__device__ __forceinline__ v2f pk_add(v2f a, v2f b) {
    v2f d; asm("v_pk_add_f32 %0, %1, %2" : "=v"(d) : "v"(a), "v"(b)); return d;
}
__device__ __forceinline__ v2f pk_mul(v2f a, v2f b) {
    v2f d; asm("v_pk_mul_f32 %0, %1, %2" : "=v"(d) : "v"(a), "v"(b)); return d;
}
__device__ __forceinline__ v2f pk_fma(v2f a, v2f b, v2f c) {
    v2f d; asm("v_pk_fma_f32 %0, %1, %2, %3" : "=v"(d) : "v"(a), "v"(b), "v"(c)); return d;
}

// ---------------- kernel B: per (point-quad, chunk) partial argmin
// 2 candidates/pk-op x 4 points/thread; LDS-staged codebook read 1x per 4 points
__global__ __launch_bounds__(256) void vq_partial_kernel(
        const float* __restrict__ z, const v2f* __restrict__ Epk,
        const v2f* __restrict__ eev,
        float* __restrict__ wd, int* __restrict__ wi) {
    __shared__ alignas(16) v2f sE[PAIRS_PER_CHUNK * 4];   // 8 KB: pair-interleaved e components
    __shared__ alignas(16) v2f see[PAIRS_PER_CHUNK];      // 2 KB: pair ee values

    const int c = blockIdx.y;                 // candidate chunk

    // ---- stage chunk slice to LDS (coalesced float4 vector loads)
    {
        const float4* gE = (const float4*)(Epk + (size_t)c * PAIRS_PER_CHUNK * 4); // 512 float4
        float4* sE4 = (float4*)sE;
        sE4[threadIdx.x] = gE[threadIdx.x];
        sE4[256 + threadIdx.x] = gE[256 + threadIdx.x];
        if (threadIdx.x < 128) {
            const float4* ge2 = (const float4*)(eev + (size_t)c * PAIRS_PER_CHUNK); // 128 float4
            ((float4*)see)[threadIdx.x] = ge2[threadIdx.x];
        }
    }

    const int n0 = blockIdx.x * (256 * PPT) + threadIdx.x;

    // ---- load 4 points; zz via mul + sequential adds (matches reference exactly)
    v2f zv[PPT][4], zzv[PPT];
    #pragma unroll
    for (int p = 0; p < PPT; ++p) {
        int n = n0 + p * 256;
        int b = n >> 12;
        int hw = n & 4095;
        const float* zp = z + b * 16384 + hw;
        float z0 = zp[0];
        float z1 = zp[CSTRIDE];
        float z2 = zp[2 * CSTRIDE];
        float z3 = zp[3 * CSTRIDE];
        float zz = __fmul_rn(z0, z0);
        zz = __fadd_rn(zz, __fmul_rn(z1, z1));
        zz = __fadd_rn(zz, __fmul_rn(z2, z2));
        zz = __fadd_rn(zz, __fmul_rn(z3, z3));
        zv[p][0] = (v2f){z0, z0};
        zv[p][1] = (v2f){z1, z1};
        zv[p][2] = (v2f){z2, z2};
        zv[p][3] = (v2f){z3, z3};
        zzv[p] = (v2f){zz, zz};
    }
    const v2f m2v = {-2.0f, -2.0f};

    __syncthreads();

    float bdl[PPT], bdh[PPT];
    int bpl[PPT], bph[PPT];
    #pragma unroll
    for (int p = 0; p < PPT; ++p) {
        bdl[p] = __builtin_inff(); bdh[p] = __builtin_inff();
        bpl[p] = 0; bph[p] = 0;
    }

    const float4* sE4 = (const float4*)sE;
    #pragma unroll 4
    for (int t = 0; t < PAIRS_PER_CHUNK; ++t) {
        // uniform LDS reads -> hardware broadcast, no bank conflicts
        float4 E01 = sE4[2 * t];       // {e0.lo,e0.hi, e1.lo,e1.hi}
        float4 E23 = sE4[2 * t + 1];   // {e2.lo,e2.hi, e3.lo,e3.hi}
        v2f ee2 = see[t];
        v2f e0 = {E01.x, E01.y};
        v2f e1 = {E01.z, E01.w};
        v2f e2 = {E23.x, E23.y};
        v2f e3 = {E23.z, E23.w};
        #pragma unroll
        for (int p = 0; p < PPT; ++p) {
            // per-half arithmetic identical to the scalar reference chain:
            v2f szz = pk_add(zzv[p], ee2);        // zz + ee_j         (rn)
            v2f dot = pk_mul(zv[p][0], e0);       // z0*e0             (rn)
            dot = pk_fma(zv[p][1], e1, dot);      // ascending-k fma chain
            dot = pk_fma(zv[p][2], e2, dot);
            dot = pk_fma(zv[p][3], e3, dot);
            v2f d2 = pk_fma(m2v, dot, szz);       // (zz+ee) - 2*dot (2*dot exact)
            if (d2.x < bdl[p]) { bdl[p] = d2.x; bpl[p] = t; }  // strict <: first index wins
            if (d2.y < bdh[p]) { bdh[p] = d2.y; bph[p] = t; }
        }
    }

    // ---- resolve halves with global first-index tie-break, write partials
    const int p0 = c * PAIRS_PER_CHUNK;
    #pragma unroll
    for (int p = 0; p < PPT; ++p) {
        int n = n0 + p * 256;
        int il = 2 * (p0 + bpl[p]), ih = 2 * (p0 + bph[p]) + 1;
        float bestd; int besti;
        if (bdh[p] < bdl[p]) { bestd = bdh[p]; besti = ih; }
        else { bestd = bdl[p]; besti = (bdl[p] == bdh[p] && ih < il) ? ih : il; }
        wd[c * N_POINTS + n] = bestd;
        wi[c * N_POINTS + n] = besti;
    }
}

// ---------------- kernel C: combine chunks, write z_q_ste (NCHW), idx-as-float, loss partials
__global__ __launch_bounds__(256) void vq_finalize_kernel(
        const float* __restrict__ z, const float4* __restrict__ E,
        const float* __restrict__ wd, const int* __restrict__ wi,
        float* __restrict__ out, double* __restrict__ partial) {
    __shared__ double sdata[256];
    int n = blockIdx.x * 256 + threadIdx.x;
    float bestd = __builtin_inff();
    int besti = 0;
    #pragma unroll
    for (int c = 0; c < CHUNKS; ++c) {           // ascending chunk + strict < -> global first-min
        float d = wd[c * N_POINTS + n];
        int i = wi[c * N_POINTS + n];
        if (d < bestd) { bestd = d; besti = i; }
    }
    int b = n >> 12;
    int hw = n & 4095;
    const float* zp = z + b * 16384 + hw;
    float* op = out + b * 16384 + hw;
    float4 e = E[besti];
    float ec[4] = {e.x, e.y, e.z, e.w};
    double ds = 0.0;
    #pragma unroll
    for (int cc = 0; cc < 4; ++cc) {
        float zc = zp[cc * CSTRIDE];
        float t = __fsub_rn(ec[cc], zc);         // z_q - z (the sg'd diff, also loss diff)
        float q = __fadd_rn(zc, t);              // straight-through: z + (z_q - z)
        op[cc * CSTRIDE] = q;
        float t2 = __fmul_rn(t, t);
        ds += (double)t2;
    }
    out[131073 + n] = (float)besti;              // indices as float32 (exact)

    sdata[threadIdx.x] = ds;
    __syncthreads();
    #pragma unroll
    for (int s = 128; s > 0; s >>= 1) {
        if (threadIdx.x < s) sdata[threadIdx.x] += sdata[threadIdx.x + s];
        __syncthreads();
    }
    if (threadIdx.x == 0) partial[blockIdx.x] = sdata[0];
}

// ---------------- kernel D: deterministic loss reduce
__global__ void vq_loss_kernel(const double* __restrict__ partial, float* __restrict__ out) {
    __shared__ double sdata[128];
    int t = threadIdx.x;
    sdata[t] = partial[t];
    __syncthreads();
    #pragma unroll
    for (int s = 64; s > 0; s >>= 1) {
        if (t < s) sdata[t] += sdata[t + s];
        __syncthreads();
    }
    if (t == 0) {
        float m = (float)(sdata[0] / 131072.0);
        // loss = mean + BETA*mean (both means are numerically identical)
        out[131072] = __fadd_rn(m, __fmul_rn(0.25f, m));
    }
}

extern "C" void kernel_launch(void* const* d_in, const int* in_sizes, int n_in,
                              void* d_out, int out_size, void* d_ws, size_t ws_size,
                              hipStream_t stream) {
    const float* z = (const float*)d_in[0];
    const float4* E = (const float4*)d_in[1];
    float* out = (float*)d_out;

    char* ws = (char*)d_ws;
    v2f* Epk = (v2f*)ws;                                     // 4096*4 v2f = 128 KB
    v2f* eev = (v2f*)(ws + 131072);                          // 4096 v2f = 32 KB
    float* wd = (float*)(ws + 131072 + 32768);               // 16*32768 f32 = 2 MB
    int*   wi = (int*)(ws + 131072 + 32768 + (size_t)CHUNKS * N_POINTS * 4); // 2 MB
    double* partial = (double*)(ws + 131072 + 32768 + (size_t)CHUNKS * N_POINTS * 8); // 1 KB

    vq_prep_kernel<<<NPAIRS / 256, 256, 0, stream>>>(E, Epk, eev);
    vq_partial_kernel<<<dim3(N_POINTS / (256 * PPT), CHUNKS), 256, 0, stream>>>(z, Epk, eev, wd, wi);
    vq_finalize_kernel<<<N_POINTS / 256, 256, 0, stream>>>(z, E, wd, wi, out, partial);
    vq_loss_kernel<<<1, 128, 0, stream>>>(partial, out);
}

// Round 5
// 62.647 us; speedup vs baseline: 1.1680x; 1.1020x over previous
//
#include <hip/hip_runtime.h>
#include <math.h>

typedef float v2f __attribute__((ext_vector_type(2)));

#define N_POINTS 32768
#define NUM_EMBED 8192
#define NPAIRS 4096
#define CHUNKS 16
#define PAIRS_PER_CHUNK (NPAIRS / CHUNKS)   // 256 pairs = 512 candidates per chunk
#define GROUPS_PER_CHUNK (PAIRS_PER_CHUNK / 4) // 64 groups of 4 pairs (8 candidates)
#define PPT 2                                // points per thread
#define CSTRIDE 4096                         // 64*64, channel stride in z [B,C,H,W]

// ---------------- kernel A: build pair-interleaved codebook + ee (exact XLA arithmetic)
__global__ void vq_prep_kernel(const float4* __restrict__ E,
                               v2f* __restrict__ Epk, v2f* __restrict__ eev) {
    int p = blockIdx.x * 256 + threadIdx.x;
    if (p < NPAIRS) {
        float4 a = E[2 * p];
        float4 b = E[2 * p + 1];
        Epk[4 * p + 0] = (v2f){a.x, b.x};
        Epk[4 * p + 1] = (v2f){a.y, b.y};
        Epk[4 * p + 2] = (v2f){a.z, b.z};
        Epk[4 * p + 3] = (v2f){a.w, b.w};
        float ea = __fmul_rn(a.x, a.x);
        ea = __fadd_rn(ea, __fmul_rn(a.y, a.y));
        ea = __fadd_rn(ea, __fmul_rn(a.z, a.z));
        ea = __fadd_rn(ea, __fmul_rn(a.w, a.w));
        float eb = __fmul_rn(b.x, b.x);
        eb = __fadd_rn(eb, __fmul_rn(b.y, b.y));
        eb = __fadd_rn(eb, __fmul_rn(b.z, b.z));
        eb = __fadd_rn(eb, __fmul_rn(b.w, b.w));
        eev[p] = (v2f){ea, eb};
    }
}

// packed f32 ops forced via inline asm (per-half IEEE rn, bit-identical to scalar chain)
__device__ __forceinline__ v2f pk_add(v2f a, v2f b) {
    v2f d; asm("v_pk_add_f32 %0, %1, %2" : "=v"(d) : "v"(a), "v"(b)); return d;
}
__device__ __forceinline__ v2f pk_mul(v2f a, v2f b) {
    v2f d; asm("v_pk_mul_f32 %0, %1, %2" : "=v"(d) : "v"(a), "v"(b)); return d;
}
__device__ __forceinline__ v2f pk_fma(v2f a, v2f b, v2f c) {
    v2f d; asm("v_pk_fma_f32 %0, %1, %2, %3" : "=v"(d) : "v"(a), "v"(b), "v"(c)); return d;
}

// ---------------- kernel B: per (point, chunk) group-tournament argmin
// 2 candidates/pk-op x 2 points/thread; tracks min PER GROUP of 8 candidates only.
__global__ __launch_bounds__(256) void vq_partial_kernel(
        const float* __restrict__ z, const v2f* __restrict__ Epk,
        const v2f* __restrict__ eev,
        float* __restrict__ wd, int* __restrict__ wg) {
    __shared__ alignas(16) v2f sE[PAIRS_PER_CHUNK * 4];   // 8 KB: pair-interleaved e components
    __shared__ alignas(16) v2f see[PAIRS_PER_CHUNK];      // 2 KB: pair ee values

    const int c = blockIdx.y;                 // candidate chunk

    // ---- stage chunk slice to LDS (coalesced float4 vector loads)
    {
        const float4* gE = (const float4*)(Epk + (size_t)c * PAIRS_PER_CHUNK * 4); // 512 float4
        float4* sE4w = (float4*)sE;
        sE4w[threadIdx.x] = gE[threadIdx.x];
        sE4w[256 + threadIdx.x] = gE[256 + threadIdx.x];
        if (threadIdx.x < 128) {
            const float4* ge2 = (const float4*)(eev + (size_t)c * PAIRS_PER_CHUNK); // 128 float4
            ((float4*)see)[threadIdx.x] = ge2[threadIdx.x];
        }
    }

    const int n0 = blockIdx.x * (256 * PPT) + threadIdx.x;

    // ---- load 2 points; zz via mul + sequential adds (matches reference exactly)
    v2f z0v[4], z1v[4], zz0v, zz1v;
    {
        int n = n0;
        int b = n >> 12, hw = n & 4095;
        const float* zp = z + b * 16384 + hw;
        float a0 = zp[0], a1 = zp[CSTRIDE], a2 = zp[2 * CSTRIDE], a3 = zp[3 * CSTRIDE];
        float zz = __fmul_rn(a0, a0);
        zz = __fadd_rn(zz, __fmul_rn(a1, a1));
        zz = __fadd_rn(zz, __fmul_rn(a2, a2));
        zz = __fadd_rn(zz, __fmul_rn(a3, a3));
        z0v[0] = (v2f){a0, a0}; z0v[1] = (v2f){a1, a1};
        z0v[2] = (v2f){a2, a2}; z0v[3] = (v2f){a3, a3};
        zz0v = (v2f){zz, zz};
    }
    {
        int n = n0 + 256;
        int b = n >> 12, hw = n & 4095;
        const float* zp = z + b * 16384 + hw;
        float a0 = zp[0], a1 = zp[CSTRIDE], a2 = zp[2 * CSTRIDE], a3 = zp[3 * CSTRIDE];
        float zz = __fmul_rn(a0, a0);
        zz = __fadd_rn(zz, __fmul_rn(a1, a1));
        zz = __fadd_rn(zz, __fmul_rn(a2, a2));
        zz = __fadd_rn(zz, __fmul_rn(a3, a3));
        z1v[0] = (v2f){a0, a0}; z1v[1] = (v2f){a1, a1};
        z1v[2] = (v2f){a2, a2}; z1v[3] = (v2f){a3, a3};
        zz1v = (v2f){zz, zz};
    }
    const v2f m2v = {-2.0f, -2.0f};

    __syncthreads();

    const float4* sE4 = (const float4*)sE;
    const float4* see4 = (const float4*)see;
    const int base_gid = c * GROUPS_PER_CHUNK;

    float bd0 = __builtin_inff(), bd1 = __builtin_inff();
    int bg0 = base_gid, bg1 = base_gid;

    #pragma unroll 2
    for (int g = 0; g < GROUPS_PER_CHUNK; ++g) {
        float4 te[8], tee[2];
        #pragma unroll
        for (int k = 0; k < 8; ++k) te[k] = sE4[8 * g + k];
        tee[0] = see4[2 * g];
        tee[1] = see4[2 * g + 1];

        float m0[4], m1[4];
        #pragma unroll
        for (int k = 0; k < 4; ++k) {
            v2f e0 = {te[2 * k].x, te[2 * k].y};
            v2f e1 = {te[2 * k].z, te[2 * k].w};
            v2f e2 = {te[2 * k + 1].x, te[2 * k + 1].y};
            v2f e3 = {te[2 * k + 1].z, te[2 * k + 1].w};
            v2f eek = (k & 2) ? ((k & 1) ? (v2f){tee[1].z, tee[1].w} : (v2f){tee[1].x, tee[1].y})
                              : ((k & 1) ? (v2f){tee[0].z, tee[0].w} : (v2f){tee[0].x, tee[0].y});
            // per-half arithmetic identical to the scalar reference chain:
            v2f szz0 = pk_add(zz0v, eek);
            v2f dot0 = pk_mul(z0v[0], e0);
            dot0 = pk_fma(z0v[1], e1, dot0);
            dot0 = pk_fma(z0v[2], e2, dot0);
            dot0 = pk_fma(z0v[3], e3, dot0);
            v2f d0 = pk_fma(m2v, dot0, szz0);
            m0[k] = fminf(d0.x, d0.y);           // exact selection, no NaNs possible
            v2f szz1 = pk_add(zz1v, eek);
            v2f dot1 = pk_mul(z1v[0], e0);
            dot1 = pk_fma(z1v[1], e1, dot1);
            dot1 = pk_fma(z1v[2], e2, dot1);
            dot1 = pk_fma(z1v[3], e3, dot1);
            v2f d1 = pk_fma(m2v, dot1, szz1);
            m1[k] = fminf(d1.x, d1.y);
        }
        float r0 = fminf(fminf(m0[0], m0[1]), fminf(m0[2], m0[3]));
        float r1 = fminf(fminf(m1[0], m1[1]), fminf(m1[2], m1[3]));
        int gid = base_gid + g;
        if (r0 < bd0) { bd0 = r0; bg0 = gid; }   // strict <: first group achieving min wins
        if (r1 < bd1) { bd1 = r1; bg1 = gid; }
    }

    wd[c * N_POINTS + n0] = bd0;
    wg[c * N_POINTS + n0] = bg0;
    wd[c * N_POINTS + n0 + 256] = bd1;
    wg[c * N_POINTS + n0 + 256] = bg1;
}

// ---------------- kernel C: combine chunks, rescan winning group exactly, write outputs
__global__ __launch_bounds__(256) void vq_finalize_kernel(
        const float* __restrict__ z, const float4* __restrict__ E,
        const float* __restrict__ wd, const int* __restrict__ wg,
        float* __restrict__ out, double* __restrict__ partial) {
    __shared__ double sdata[256];
    int n = blockIdx.x * 256 + threadIdx.x;
    float bestd = __builtin_inff();
    int bgrp = 0;
    #pragma unroll
    for (int c = 0; c < CHUNKS; ++c) {           // ascending chunk + strict < -> global first group
        float d = wd[c * N_POINTS + n];
        int gi = wg[c * N_POINTS + n];
        if (d < bestd) { bestd = d; bgrp = gi; }
    }
    int b = n >> 12;
    int hw = n & 4095;
    const float* zp = z + b * 16384 + hw;
    float z0 = zp[0];
    float z1 = zp[CSTRIDE];
    float z2 = zp[2 * CSTRIDE];
    float z3 = zp[3 * CSTRIDE];
    float zz = __fmul_rn(z0, z0);
    zz = __fadd_rn(zz, __fmul_rn(z1, z1));
    zz = __fadd_rn(zz, __fmul_rn(z2, z2));
    zz = __fadd_rn(zz, __fmul_rn(z3, z3));

    // rescan the winning group's 8 candidates with the exact scalar chain;
    // descending scan + (d == bestd) overwrite = smallest j wins (first-index tie-break)
    int j0 = bgrp << 3;
    int besti = j0;
    #pragma unroll
    for (int k = 7; k >= 0; --k) {
        int j = j0 + k;
        float4 e = E[j];
        float ee = __fmul_rn(e.x, e.x);
        ee = __fadd_rn(ee, __fmul_rn(e.y, e.y));
        ee = __fadd_rn(ee, __fmul_rn(e.z, e.z));
        ee = __fadd_rn(ee, __fmul_rn(e.w, e.w));
        float dot = __fmul_rn(z0, e.x);
        dot = __fmaf_rn(z1, e.y, dot);
        dot = __fmaf_rn(z2, e.z, dot);
        dot = __fmaf_rn(z3, e.w, dot);
        float d = __fmaf_rn(-2.0f, dot, __fadd_rn(zz, ee));
        if (d == bestd) besti = j;
    }

    float* op = out + b * 16384 + hw;
    float4 e = E[besti];
    float ec[4] = {e.x, e.y, e.z, e.w};
    float zc[4] = {z0, z1, z2, z3};
    double ds = 0.0;
    #pragma unroll
    for (int cc = 0; cc < 4; ++cc) {
        float t = __fsub_rn(ec[cc], zc[cc]);     // z_q - z (the sg'd diff, also loss diff)
        float q = __fadd_rn(zc[cc], t);          // straight-through: z + (z_q - z)
        op[cc * CSTRIDE] = q;
        float t2 = __fmul_rn(t, t);
        ds += (double)t2;
    }
    out[131073 + n] = (float)besti;              // indices as float32 (exact)

    sdata[threadIdx.x] = ds;
    __syncthreads();
    #pragma unroll
    for (int s = 128; s > 0; s >>= 1) {
        if (threadIdx.x < s) sdata[threadIdx.x] += sdata[threadIdx.x + s];
        __syncthreads();
    }
    if (threadIdx.x == 0) partial[blockIdx.x] = sdata[0];
}

// ---------------- kernel D: deterministic loss reduce
__global__ void vq_loss_kernel(const double* __restrict__ partial, float* __restrict__ out) {
    __shared__ double sdata[128];
    int t = threadIdx.x;
    sdata[t] = partial[t];
    __syncthreads();
    #pragma unroll
    for (int s = 64; s > 0; s >>= 1) {
        if (t < s) sdata[t] += sdata[t + s];
        __syncthreads();
    }
    if (t == 0) {
        float m = (float)(sdata[0] / 131072.0);
        // loss = mean + BETA*mean (both means are numerically identical)
        out[131072] = __fadd_rn(m, __fmul_rn(0.25f, m));
    }
}

extern "C" void kernel_launch(void* const* d_in, const int* in_sizes, int n_in,
                              void* d_out, int out_size, void* d_ws, size_t ws_size,
                              hipStream_t stream) {
    const float* z = (const float*)d_in[0];
    const float4* E = (const float4*)d_in[1];
    float* out = (float*)d_out;

    char* ws = (char*)d_ws;
    v2f* Epk = (v2f*)ws;                                     // 4096*4 v2f = 128 KB
    v2f* eev = (v2f*)(ws + 131072);                          // 4096 v2f = 32 KB
    float* wd = (float*)(ws + 131072 + 32768);               // 16*32768 f32 = 2 MB
    int*   wg = (int*)(ws + 131072 + 32768 + (size_t)CHUNKS * N_POINTS * 4); // 2 MB
    double* partial = (double*)(ws + 131072 + 32768 + (size_t)CHUNKS * N_POINTS * 8); // 1 KB

    vq_prep_kernel<<<NPAIRS / 256, 256, 0, stream>>>(E, Epk, eev);
    vq_partial_kernel<<<dim3(N_POINTS / (256 * PPT), CHUNKS), 256, 0, stream>>>(z, Epk, eev, wd, wg);
    vq_finalize_kernel<<<N_POINTS / 256, 256, 0, stream>>>(z, E, wd, wg, out, partial);
    vq_loss_kernel<<<1, 128, 0, stream>>>(partial, out);
}